// Round 2
// baseline (172.073 us; speedup 1.0000x reference)
//
#include <hip/hip_runtime.h>
#include <math.h>

// Amortized VI: per-row 3 MLPs (2->20->10->{4,4,6}), Cholesky reparam over
// P=8 samples, robot-arm forward kinematics likelihood, global mean.
//
// Constants folded:
//  C_PRIOR = -(log .25 + 3 log .5) - 2*log(2pi)   = -0.210018230
//  C_LIK   = -2*log(.01) - log(2pi)               =  7.372463306
//  C_ENT   = 0.5*4*(1+log(2pi))                   =  5.675754132
//  sum = 12.838199208
#define C_ALL 12.838199208f

struct WPtrs { const float* p[18]; };

__device__ __forceinline__ float softplus_f(float x) {
    // stable: max(x,0) + log1p(exp(-|x|))
    return fmaxf(x, 0.0f) + __logf(1.0f + __expf(-fabsf(x)));
}

// MLP: y[2] @ W1[2][20] + b1 -> relu -> @ W2[20][10] + b2 -> relu -> @ W3[10][OD] + b3
// LDS layout at base o: W1(40) b1(20) W2(200) b2(10) W3(10*OD) b3(OD)
template <int OD>
__device__ __forceinline__ void mlp_eval(const float* __restrict__ w, int o,
                                         float y0, float y1, float* out) {
    float h1[20];
#pragma unroll
    for (int j = 0; j < 20; ++j)
        h1[j] = fmaxf(0.0f, fmaf(y0, w[o + j], fmaf(y1, w[o + 20 + j], w[o + 40 + j])));
    float h2[10];
#pragma unroll
    for (int k = 0; k < 10; ++k) h2[k] = w[o + 260 + k];
#pragma unroll
    for (int j = 0; j < 20; ++j) {
#pragma unroll
        for (int k = 0; k < 10; ++k)
            h2[k] = fmaf(h1[j], w[o + 60 + j * 10 + k], h2[k]);
    }
#pragma unroll
    for (int k = 0; k < 10; ++k) h2[k] = fmaxf(0.0f, h2[k]);
#pragma unroll
    for (int d = 0; d < OD; ++d) out[d] = w[o + 270 + 10 * OD + d];  // b3
#pragma unroll
    for (int k = 0; k < 10; ++k) {
#pragma unroll
        for (int d = 0; d < OD; ++d)
            out[d] = fmaf(h2[k], w[o + 270 + k * OD + d], out[d]);
    }
}

__global__ __launch_bounds__(256) void avi_kernel(
    const float* __restrict__ y, const float* __restrict__ zs, WPtrs wp,
    float* __restrict__ out, int N, float invN) {
    __shared__ float w[964];
    __shared__ float wsum[4];

    const int tid = threadIdx.x;
    // Cooperative weight staging. Offsets: mu@0 (314), ld@314 (314), lo@628 (336).
    {
        const int sizes[18] = {40, 20, 200, 10, 40, 4,
                               40, 20, 200, 10, 40, 4,
                               40, 20, 200, 10, 60, 6};
        int off = 0;
#pragma unroll
        for (int a = 0; a < 18; ++a) {
            for (int i = tid; i < sizes[a]; i += 256) w[off + i] = wp.p[a][i];
            off += sizes[a];
        }
    }
    __syncthreads();

    const int n = blockIdx.x * 256 + tid;
    float rowval = 0.0f;
    if (n < N) {
        const float2 yv = *reinterpret_cast<const float2*>(y + 2 * (size_t)n);
        const float y0 = yv.x, y1 = yv.y;

        float mu[4], ldr[4], lo[6];
        mlp_eval<4>(w, 0, y0, y1, mu);
        mlp_eval<4>(w, 314, y0, y1, ldr);
        mlp_eval<6>(w, 628, y0, y1, lo);

        const float d0 = softplus_f(ldr[0]);
        const float d1 = softplus_f(ldr[1]);
        const float d2 = softplus_f(ldr[2]);
        const float d3 = softplus_f(ldr[3]);
        const float sumlogdiag = __logf(d0) + __logf(d1) + __logf(d2) + __logf(d3);
        // strict-lower tril order: (1,0),(2,0),(2,1),(3,0),(3,1),(3,2)
        const float L10 = lo[0], L20 = lo[1], L21 = lo[2];
        const float L30 = lo[3], L31 = lo[4], L32 = lo[5];

        const float4* zp = reinterpret_cast<const float4*>(zs + (size_t)n * 32);
        float acc = 0.0f;
#pragma unroll
        for (int p = 0; p < 8; ++p) {
            const float4 z = zp[p];
            const float xi0 = fmaf(d0, z.x, mu[0]);
            const float xi1 = fmaf(d1, z.y, fmaf(L10, z.x, mu[1]));
            const float xi2 = fmaf(d2, z.z, fmaf(L21, z.y, fmaf(L20, z.x, mu[2])));
            const float xi3 = fmaf(d3, z.w, fmaf(L32, z.z, fmaf(L31, z.y, fmaf(L30, z.x, mu[3]))));

            const float a1 = xi1, a2 = xi1 + xi2, a3 = a2 + xi3;
            float s1, c1, s2, c2, s3, c3;
            __sincosf(a1, &s1, &c1);
            __sincosf(a2, &s2, &c2);
            __sincosf(a3, &s3, &c3);
            const float px = fmaf(0.5f, c1, fmaf(0.5f, c2, c3));
            const float py = xi0 + fmaf(0.5f, s1, fmaf(0.5f, s2, s3));

            // prior quad: (xi/prior_scale)^2, scales [.25,.5,.5,.5]
            const float q0 = xi0 * 4.0f, q1 = xi1 * 2.0f, q2 = xi2 * 2.0f, q3 = xi3 * 2.0f;
            const float pq = fmaf(q0, q0, fmaf(q1, q1, fmaf(q2, q2, q3 * q3)));
            // likelihood residuals: (y - D)/0.01
            const float r0 = (y0 - px) * 100.0f;
            const float r1 = (y1 - py) * 100.0f;
            acc = fmaf(-0.5f, pq + fmaf(r0, r0, r1 * r1), acc);
        }
        rowval = fmaf(0.125f, acc, C_ALL + sumlogdiag);
    }

    // wave (64) shuffle reduce, then cross-wave via LDS
#pragma unroll
    for (int d = 32; d > 0; d >>= 1) rowval += __shfl_down(rowval, d);
    if ((tid & 63) == 0) wsum[tid >> 6] = rowval;
    __syncthreads();
    if (tid == 0) {
        const float s = wsum[0] + wsum[1] + wsum[2] + wsum[3];
        atomicAdd(out, s * invN);
    }
}

extern "C" void kernel_launch(void* const* d_in, const int* in_sizes, int n_in,
                              void* d_out, int out_size, void* d_ws, size_t ws_size,
                              hipStream_t stream) {
    const float* y = (const float*)d_in[0];
    const float* zs = (const float*)d_in[1];
    WPtrs wp;
    for (int i = 0; i < 18; ++i) wp.p[i] = (const float*)d_in[2 + i];
    float* out = (float*)d_out;
    const int N = in_sizes[0] / 2;

    hipMemsetAsync(out, 0, sizeof(float), stream);
    const int blocks = (N + 255) / 256;
    avi_kernel<<<blocks, 256, 0, stream>>>(y, zs, wp, out, N, 1.0f / (float)N);
}

// Round 3
// 161.207 us; speedup vs baseline: 1.0674x; 1.0674x over previous
//
#include <hip/hip_runtime.h>
#include <math.h>

// Amortized VI: per-row 3 MLPs (2->20->10->{4,4,6}), Cholesky reparam over
// P=8 samples, robot-arm forward kinematics likelihood, global mean.
//
// R2 insight: weights read via LDS broadcast = 964 ds_read_b32/row-wave,
// LDS pipe (per-CU, ~5.8cyc/op) -> 74us floor == measured 83us. Fix: read
// weights straight from global with wave-uniform addresses -> s_load (SMEM
// pipe, K$-cached), zero LDS traffic.
//
// Constants folded:
//  C_PRIOR = -(log .25 + 3 log .5) - 2*log(2pi)   = -0.210018230
//  C_LIK   = -2*log(.01) - log(2pi)               =  7.372463306
//  C_ENT   = 0.5*4*(1+log(2pi))                   =  5.675754132
//  sum = 12.838199208
#define C_ALL 12.838199208f

struct WPtrs { const float* p[18]; };

__device__ __forceinline__ float softplus_f(float x) {
    return fmaxf(x, 0.0f) + __logf(1.0f + __expf(-fabsf(x)));
}

// MLP: y[2] @ W1[2][20] + b1 -> relu -> @ W2[20][10] + b2 -> relu -> @ W3[10][OD] + b3
// All weight reads are wave-uniform -> scalar loads (SMEM), SGPR operands to FMAs.
template <int OD>
__device__ __forceinline__ void mlp_eval(const float* __restrict__ W1,
                                         const float* __restrict__ b1,
                                         const float* __restrict__ W2,
                                         const float* __restrict__ b2,
                                         const float* __restrict__ W3,
                                         const float* __restrict__ b3,
                                         float y0, float y1, float* out) {
    float h1[20];
#pragma unroll
    for (int j = 0; j < 20; ++j)
        h1[j] = fmaxf(0.0f, fmaf(y0, W1[j], fmaf(y1, W1[20 + j], b1[j])));
    float h2[10];
#pragma unroll
    for (int k = 0; k < 10; ++k) h2[k] = b2[k];
#pragma unroll
    for (int j = 0; j < 20; ++j) {
#pragma unroll
        for (int k = 0; k < 10; ++k)
            h2[k] = fmaf(h1[j], W2[j * 10 + k], h2[k]);
    }
#pragma unroll
    for (int k = 0; k < 10; ++k) h2[k] = fmaxf(0.0f, h2[k]);
#pragma unroll
    for (int d = 0; d < OD; ++d) out[d] = b3[d];
#pragma unroll
    for (int k = 0; k < 10; ++k) {
#pragma unroll
        for (int d = 0; d < OD; ++d)
            out[d] = fmaf(h2[k], W3[k * OD + d], out[d]);
    }
}

__global__ __launch_bounds__(256) void avi_kernel(
    const float* __restrict__ y, const float* __restrict__ zs, WPtrs wp,
    float* __restrict__ out, int N, float invN) {
    __shared__ float wsum[4];

    const int tid = threadIdx.x;
    const int n = blockIdx.x * 256 + tid;
    float rowval = 0.0f;
    if (n < N) {
        const float2 yv = *reinterpret_cast<const float2*>(y + 2 * (size_t)n);
        const float y0 = yv.x, y1 = yv.y;

        float mu[4], ldr[4], lo[6];
        mlp_eval<4>(wp.p[0], wp.p[1], wp.p[2], wp.p[3], wp.p[4], wp.p[5], y0, y1, mu);
        mlp_eval<4>(wp.p[6], wp.p[7], wp.p[8], wp.p[9], wp.p[10], wp.p[11], y0, y1, ldr);
        mlp_eval<6>(wp.p[12], wp.p[13], wp.p[14], wp.p[15], wp.p[16], wp.p[17], y0, y1, lo);

        const float d0 = softplus_f(ldr[0]);
        const float d1 = softplus_f(ldr[1]);
        const float d2 = softplus_f(ldr[2]);
        const float d3 = softplus_f(ldr[3]);
        const float sumlogdiag = __logf(d0 * d1 * d2 * d3);
        // strict-lower tril order: (1,0),(2,0),(2,1),(3,0),(3,1),(3,2)
        const float L10 = lo[0], L20 = lo[1], L21 = lo[2];
        const float L30 = lo[3], L31 = lo[4], L32 = lo[5];

        const float4* zp = reinterpret_cast<const float4*>(zs + (size_t)n * 32);
        float acc = 0.0f;
#pragma unroll
        for (int p = 0; p < 8; ++p) {
            const float4 z = zp[p];
            const float xi0 = fmaf(d0, z.x, mu[0]);
            const float xi1 = fmaf(d1, z.y, fmaf(L10, z.x, mu[1]));
            const float xi2 = fmaf(d2, z.z, fmaf(L21, z.y, fmaf(L20, z.x, mu[2])));
            const float xi3 = fmaf(d3, z.w, fmaf(L32, z.z, fmaf(L31, z.y, fmaf(L30, z.x, mu[3]))));

            const float a1 = xi1, a2 = xi1 + xi2, a3 = a2 + xi3;
            float s1, c1, s2, c2, s3, c3;
            __sincosf(a1, &s1, &c1);
            __sincosf(a2, &s2, &c2);
            __sincosf(a3, &s3, &c3);
            const float px = fmaf(0.5f, c1, fmaf(0.5f, c2, c3));
            const float py = xi0 + fmaf(0.5f, s1, fmaf(0.5f, s2, s3));

            // prior quad: (xi/prior_scale)^2, scales [.25,.5,.5,.5]
            const float q0 = xi0 * 4.0f, q1 = xi1 * 2.0f, q2 = xi2 * 2.0f, q3 = xi3 * 2.0f;
            const float pq = fmaf(q0, q0, fmaf(q1, q1, fmaf(q2, q2, q3 * q3)));
            // likelihood residuals: (y - D)/0.01
            const float r0 = (y0 - px) * 100.0f;
            const float r1 = (y1 - py) * 100.0f;
            acc = fmaf(-0.5f, pq + fmaf(r0, r0, r1 * r1), acc);
        }
        rowval = fmaf(0.125f, acc, C_ALL + sumlogdiag);
    }

    // wave (64) shuffle reduce, then cross-wave via LDS
#pragma unroll
    for (int d = 32; d > 0; d >>= 1) rowval += __shfl_down(rowval, d);
    if ((tid & 63) == 0) wsum[tid >> 6] = rowval;
    __syncthreads();
    if (tid == 0) {
        const float s = wsum[0] + wsum[1] + wsum[2] + wsum[3];
        atomicAdd(out, s * invN);
    }
}

extern "C" void kernel_launch(void* const* d_in, const int* in_sizes, int n_in,
                              void* d_out, int out_size, void* d_ws, size_t ws_size,
                              hipStream_t stream) {
    const float* y = (const float*)d_in[0];
    const float* zs = (const float*)d_in[1];
    WPtrs wp;
    for (int i = 0; i < 18; ++i) wp.p[i] = (const float*)d_in[2 + i];
    float* out = (float*)d_out;
    const int N = in_sizes[0] / 2;

    hipMemsetAsync(out, 0, sizeof(float), stream);
    const int blocks = (N + 255) / 256;
    avi_kernel<<<blocks, 256, 0, stream>>>(y, zs, wp, out, N, 1.0f / (float)N);
}

// Round 4
// 156.731 us; speedup vs baseline: 1.0979x; 1.0286x over previous
//
#include <hip/hip_runtime.h>
#include <math.h>

// Amortized VI: per-row 3 MLPs (2->20->10->{4,4,6}), Cholesky reparam over
// P=8 samples, robot-arm FK likelihood, global mean.
//
// R3 insight: weights (964 f32) >> SGPR file -> compiler re-issues s_load
// batches per row; lgkm latency between small FMA batches is the stall
// (VALUBusy 37%, HBM 8%, LDS 0). Fix: process 2 rows per thread with the
// MLP interleaved, so each scalar weight load feeds 2 FMAs and per-row
// SMEM cost halves.
//
// Constants folded: C_PRIOR + C_LIK + C_ENT = 12.838199208
#define C_ALL 12.838199208f

struct WPtrs { const float* p[18]; };

__device__ __forceinline__ float softplus_f(float x) {
    return fmaxf(x, 0.0f) + __logf(1.0f + __expf(-fabsf(x)));
}

// Two-row MLP: each scalar (wave-uniform, SGPR) weight feeds both rows' FMAs.
template <int OD>
__device__ __forceinline__ void mlp_eval2(const float* __restrict__ W1,
                                          const float* __restrict__ b1,
                                          const float* __restrict__ W2,
                                          const float* __restrict__ b2,
                                          const float* __restrict__ W3,
                                          const float* __restrict__ b3,
                                          float y0a, float y1a, float y0b, float y1b,
                                          float* oa, float* ob) {
    float h1a[20], h1b[20];
#pragma unroll
    for (int j = 0; j < 20; ++j) {
        const float w0 = W1[j], w1 = W1[20 + j], bb = b1[j];
        h1a[j] = fmaxf(0.0f, fmaf(y0a, w0, fmaf(y1a, w1, bb)));
        h1b[j] = fmaxf(0.0f, fmaf(y0b, w0, fmaf(y1b, w1, bb)));
    }
    float h2a[10], h2b[10];
#pragma unroll
    for (int k = 0; k < 10; ++k) {
        const float bb = b2[k];
        h2a[k] = bb; h2b[k] = bb;
    }
#pragma unroll
    for (int j = 0; j < 20; ++j) {
#pragma unroll
        for (int k = 0; k < 10; ++k) {
            const float w = W2[j * 10 + k];
            h2a[k] = fmaf(h1a[j], w, h2a[k]);
            h2b[k] = fmaf(h1b[j], w, h2b[k]);
        }
    }
#pragma unroll
    for (int k = 0; k < 10; ++k) {
        h2a[k] = fmaxf(0.0f, h2a[k]);
        h2b[k] = fmaxf(0.0f, h2b[k]);
    }
#pragma unroll
    for (int d = 0; d < OD; ++d) {
        const float bb = b3[d];
        oa[d] = bb; ob[d] = bb;
    }
#pragma unroll
    for (int k = 0; k < 10; ++k) {
#pragma unroll
        for (int d = 0; d < OD; ++d) {
            const float w = W3[k * OD + d];
            oa[d] = fmaf(h2a[k], w, oa[d]);
            ob[d] = fmaf(h2b[k], w, ob[d]);
        }
    }
}

__device__ __forceinline__ float row_tail(const float* mu, const float* ldr, const float* lo,
                                          float y0, float y1, const float4* __restrict__ zp) {
    const float d0 = softplus_f(ldr[0]);
    const float d1 = softplus_f(ldr[1]);
    const float d2 = softplus_f(ldr[2]);
    const float d3 = softplus_f(ldr[3]);
    const float sumlogdiag = __logf(d0 * d1 * d2 * d3);
    const float L10 = lo[0], L20 = lo[1], L21 = lo[2];
    const float L30 = lo[3], L31 = lo[4], L32 = lo[5];

    float acc = 0.0f;
#pragma unroll
    for (int p = 0; p < 8; ++p) {
        const float4 z = zp[p];
        const float xi0 = fmaf(d0, z.x, mu[0]);
        const float xi1 = fmaf(d1, z.y, fmaf(L10, z.x, mu[1]));
        const float xi2 = fmaf(d2, z.z, fmaf(L21, z.y, fmaf(L20, z.x, mu[2])));
        const float xi3 = fmaf(d3, z.w, fmaf(L32, z.z, fmaf(L31, z.y, fmaf(L30, z.x, mu[3]))));

        const float a1 = xi1, a2 = xi1 + xi2, a3 = a2 + xi3;
        float s1, c1, s2, c2, s3, c3;
        __sincosf(a1, &s1, &c1);
        __sincosf(a2, &s2, &c2);
        __sincosf(a3, &s3, &c3);
        const float px = fmaf(0.5f, c1, fmaf(0.5f, c2, c3));
        const float py = xi0 + fmaf(0.5f, s1, fmaf(0.5f, s2, s3));

        const float q0 = xi0 * 4.0f, q1 = xi1 * 2.0f, q2 = xi2 * 2.0f, q3 = xi3 * 2.0f;
        const float pq = fmaf(q0, q0, fmaf(q1, q1, fmaf(q2, q2, q3 * q3)));
        const float r0 = (y0 - px) * 100.0f;
        const float r1 = (y1 - py) * 100.0f;
        acc = fmaf(-0.5f, pq + fmaf(r0, r0, r1 * r1), acc);
    }
    return fmaf(0.125f, acc, C_ALL + sumlogdiag);
}

__global__ __launch_bounds__(256, 2) void avi_kernel(
    const float* __restrict__ y, const float* __restrict__ zs, WPtrs wp,
    float* __restrict__ out, int N, float invN) {
    __shared__ float wsum[4];

    const int tid = threadIdx.x;
    const int na = blockIdx.x * 512 + tid;        // row A
    const int nb = na + 256;                       // row B (coalesced second slab)
    float rv = 0.0f;
    if (nb < N) {
        const float2 ya = *reinterpret_cast<const float2*>(y + 2 * (size_t)na);
        const float2 yb = *reinterpret_cast<const float2*>(y + 2 * (size_t)nb);

        float mua[4], mub[4], lda[4], ldb[4], loa[6], lob[6];
        mlp_eval2<4>(wp.p[0], wp.p[1], wp.p[2], wp.p[3], wp.p[4], wp.p[5],
                     ya.x, ya.y, yb.x, yb.y, mua, mub);
        mlp_eval2<4>(wp.p[6], wp.p[7], wp.p[8], wp.p[9], wp.p[10], wp.p[11],
                     ya.x, ya.y, yb.x, yb.y, lda, ldb);
        mlp_eval2<6>(wp.p[12], wp.p[13], wp.p[14], wp.p[15], wp.p[16], wp.p[17],
                     ya.x, ya.y, yb.x, yb.y, loa, lob);

        const float4* zpa = reinterpret_cast<const float4*>(zs + (size_t)na * 32);
        const float4* zpb = reinterpret_cast<const float4*>(zs + (size_t)nb * 32);
        rv = row_tail(mua, lda, loa, ya.x, ya.y, zpa)
           + row_tail(mub, ldb, lob, yb.x, yb.y, zpb);
    } else if (na < N) {  // tail safety (not hit for N=524288)
        const float2 ya = *reinterpret_cast<const float2*>(y + 2 * (size_t)na);
        float mua[4], mub[4], lda[4], ldb[4], loa[6], lob[6];
        mlp_eval2<4>(wp.p[0], wp.p[1], wp.p[2], wp.p[3], wp.p[4], wp.p[5],
                     ya.x, ya.y, ya.x, ya.y, mua, mub);
        mlp_eval2<4>(wp.p[6], wp.p[7], wp.p[8], wp.p[9], wp.p[10], wp.p[11],
                     ya.x, ya.y, ya.x, ya.y, lda, ldb);
        mlp_eval2<6>(wp.p[12], wp.p[13], wp.p[14], wp.p[15], wp.p[16], wp.p[17],
                     ya.x, ya.y, ya.x, ya.y, loa, lob);
        const float4* zpa = reinterpret_cast<const float4*>(zs + (size_t)na * 32);
        rv = row_tail(mua, lda, loa, ya.x, ya.y, zpa);
    }

    // wave (64) shuffle reduce, then cross-wave via LDS
#pragma unroll
    for (int d = 32; d > 0; d >>= 1) rv += __shfl_down(rv, d);
    if ((tid & 63) == 0) wsum[tid >> 6] = rv;
    __syncthreads();
    if (tid == 0) {
        const float s = wsum[0] + wsum[1] + wsum[2] + wsum[3];
        atomicAdd(out, s * invN);
    }
}

extern "C" void kernel_launch(void* const* d_in, const int* in_sizes, int n_in,
                              void* d_out, int out_size, void* d_ws, size_t ws_size,
                              hipStream_t stream) {
    const float* y = (const float*)d_in[0];
    const float* zs = (const float*)d_in[1];
    WPtrs wp;
    for (int i = 0; i < 18; ++i) wp.p[i] = (const float*)d_in[2 + i];
    float* out = (float*)d_out;
    const int N = in_sizes[0] / 2;

    hipMemsetAsync(out, 0, sizeof(float), stream);
    const int blocks = (N + 511) / 512;
    avi_kernel<<<blocks, 256, 0, stream>>>(y, zs, wp, out, N, 1.0f / (float)N);
}

// Round 5
// 156.057 us; speedup vs baseline: 1.1026x; 1.0043x over previous
//
#include <hip/hip_runtime.h>
#include <math.h>

// Amortized VI: per-row 3 MLPs (2->20->10->{4,4,6}), Cholesky reparam over
// P=8 samples, robot-arm FK likelihood, global mean.
//
// R4 insight: latency-bound (VALU 33%, HBM 15%, LDS 0) and VALU issue count
// is the next wall. R5: pack the 2 rows/thread as float2 ext-vectors through
// MLP + tail -> v_pk_fma_f32 (VOP3P) halves packable VALU issue; a/b rows
// give 2 independent dep chains (breaks serial sincos chains) even if the
// backend declines to pack.
//
// Constants folded: C_PRIOR + C_LIK + C_ENT = 12.838199208
#define C_ALL 12.838199208f

typedef float v2 __attribute__((ext_vector_type(2)));
static __device__ __forceinline__ v2 splat(float s) { return (v2){s, s}; }
#define FMA2 __builtin_elementwise_fma
#define MAX2 __builtin_elementwise_max

struct WPtrs { const float* p[18]; };

__device__ __forceinline__ float softplus_f(float x) {
    return fmaxf(x, 0.0f) + __logf(1.0f + __expf(-fabsf(x)));
}
__device__ __forceinline__ v2 sp2(v2 x) {
    v2 r; r.x = softplus_f(x.x); r.y = softplus_f(x.y); return r;
}

// Two-row packed MLP; weights wave-uniform (SGPR), broadcast into VOP3P.
// h1 fused into the j-loop: 1 live v2 instead of 20.
template <int OD>
__device__ __forceinline__ void mlp2(const float* __restrict__ W1,
                                     const float* __restrict__ b1,
                                     const float* __restrict__ W2,
                                     const float* __restrict__ b2,
                                     const float* __restrict__ W3,
                                     const float* __restrict__ b3,
                                     v2 Y0, v2 Y1, v2* out) {
    v2 h2[10];
#pragma unroll
    for (int k = 0; k < 10; ++k) h2[k] = splat(b2[k]);
#pragma unroll
    for (int j = 0; j < 20; ++j) {
        const v2 h1 = MAX2(FMA2(Y0, splat(W1[j]), FMA2(Y1, splat(W1[20 + j]), splat(b1[j]))),
                           splat(0.0f));
#pragma unroll
        for (int k = 0; k < 10; ++k) h2[k] = FMA2(h1, splat(W2[j * 10 + k]), h2[k]);
    }
#pragma unroll
    for (int k = 0; k < 10; ++k) h2[k] = MAX2(h2[k], splat(0.0f));
#pragma unroll
    for (int d = 0; d < OD; ++d) out[d] = splat(b3[d]);
#pragma unroll
    for (int k = 0; k < 10; ++k) {
#pragma unroll
        for (int d = 0; d < OD; ++d) out[d] = FMA2(h2[k], splat(W3[k * OD + d]), out[d]);
    }
}

__global__ __launch_bounds__(256) void avi_kernel(
    const float* __restrict__ y, const float* __restrict__ zs, WPtrs wp,
    float* __restrict__ out, int N, float invN) {
    __shared__ float wsum[4];

    const int tid = threadIdx.x;
    const int na = blockIdx.x * 512 + tid;   // row A
    const int nb = na + 256;                 // row B (coalesced second slab)
    float rv = 0.0f;
    if (na < N) {
        const int mb = (nb < N) ? nb : na;   // tail: duplicate row A
        const float2 ya = *reinterpret_cast<const float2*>(y + 2 * (size_t)na);
        const float2 yb = *reinterpret_cast<const float2*>(y + 2 * (size_t)mb);
        const v2 Y0 = {ya.x, yb.x};
        const v2 Y1 = {ya.y, yb.y};

        v2 mu[4], ld[4], lo[6];
        mlp2<4>(wp.p[0], wp.p[1], wp.p[2], wp.p[3], wp.p[4], wp.p[5], Y0, Y1, mu);
        mlp2<4>(wp.p[6], wp.p[7], wp.p[8], wp.p[9], wp.p[10], wp.p[11], Y0, Y1, ld);
        mlp2<6>(wp.p[12], wp.p[13], wp.p[14], wp.p[15], wp.p[16], wp.p[17], Y0, Y1, lo);

        const v2 d0 = sp2(ld[0]), d1 = sp2(ld[1]), d2 = sp2(ld[2]), d3 = sp2(ld[3]);
        const v2 prod = d0 * d1 * d2 * d3;
        const v2 L10 = lo[0], L20 = lo[1], L21 = lo[2];
        const v2 L30 = lo[3], L31 = lo[4], L32 = lo[5];

        const float4* zpa = reinterpret_cast<const float4*>(zs + (size_t)na * 32);
        const float4* zpb = reinterpret_cast<const float4*>(zs + (size_t)mb * 32);
        v2 acc = splat(0.0f);
#pragma unroll
        for (int p = 0; p < 8; ++p) {
            const float4 za = zpa[p];
            const float4 zb = zpb[p];
            const v2 zx = {za.x, zb.x}, zy = {za.y, zb.y};
            const v2 zz = {za.z, zb.z}, zw = {za.w, zb.w};

            const v2 xi0 = FMA2(d0, zx, mu[0]);
            const v2 xi1 = FMA2(d1, zy, FMA2(L10, zx, mu[1]));
            const v2 xi2 = FMA2(d2, zz, FMA2(L21, zy, FMA2(L20, zx, mu[2])));
            const v2 xi3 = FMA2(d3, zw, FMA2(L32, zz, FMA2(L31, zy, FMA2(L30, zx, mu[3]))));

            const v2 a1 = xi1, a2 = xi1 + xi2, a3 = a2 + xi3;
            float s1x, c1x, s1y, c1y, s2x, c2x, s2y, c2y, s3x, c3x, s3y, c3y;
            __sincosf(a1.x, &s1x, &c1x);
            __sincosf(a1.y, &s1y, &c1y);
            __sincosf(a2.x, &s2x, &c2x);
            __sincosf(a2.y, &s2y, &c2y);
            __sincosf(a3.x, &s3x, &c3x);
            __sincosf(a3.y, &s3y, &c3y);
            const v2 s1 = {s1x, s1y}, c1 = {c1x, c1y};
            const v2 s2 = {s2x, s2y}, c2 = {c2x, c2y};
            const v2 s3 = {s3x, s3y}, c3 = {c3x, c3y};

            const v2 half = splat(0.5f);
            const v2 px = FMA2(half, c1, FMA2(half, c2, c3));
            const v2 py = xi0 + FMA2(half, s1, FMA2(half, s2, s3));

            const v2 q0 = xi0 * splat(4.0f), q1 = xi1 * splat(2.0f);
            const v2 q2 = xi2 * splat(2.0f), q3 = xi3 * splat(2.0f);
            const v2 pq = FMA2(q0, q0, FMA2(q1, q1, FMA2(q2, q2, q3 * q3)));
            const v2 r0 = (Y0 - px) * splat(100.0f);
            const v2 r1 = (Y1 - py) * splat(100.0f);
            acc = FMA2(splat(-0.5f), pq + FMA2(r0, r0, r1 * r1), acc);
        }
        if (nb < N) {
            rv = fmaf(0.125f, acc.x, C_ALL + __logf(prod.x))
               + fmaf(0.125f, acc.y, C_ALL + __logf(prod.y));
        } else {
            rv = fmaf(0.125f, acc.x, C_ALL + __logf(prod.x));
        }
    }

    // wave (64) shuffle reduce, then cross-wave via LDS
#pragma unroll
    for (int d = 32; d > 0; d >>= 1) rv += __shfl_down(rv, d);
    if ((tid & 63) == 0) wsum[tid >> 6] = rv;
    __syncthreads();
    if (tid == 0) {
        const float s = wsum[0] + wsum[1] + wsum[2] + wsum[3];
        atomicAdd(out, s * invN);
    }
}

extern "C" void kernel_launch(void* const* d_in, const int* in_sizes, int n_in,
                              void* d_out, int out_size, void* d_ws, size_t ws_size,
                              hipStream_t stream) {
    const float* y = (const float*)d_in[0];
    const float* zs = (const float*)d_in[1];
    WPtrs wp;
    for (int i = 0; i < 18; ++i) wp.p[i] = (const float*)d_in[2 + i];
    float* out = (float*)d_out;
    const int N = in_sizes[0] / 2;

    hipMemsetAsync(out, 0, sizeof(float), stream);
    const int blocks = (N + 511) / 512;
    avi_kernel<<<blocks, 256, 0, stream>>>(y, zs, wp, out, N, 1.0f / (float)N);
}

// Round 6
// 149.651 us; speedup vs baseline: 1.1498x; 1.0428x over previous
//
#include <hip/hip_runtime.h>
#include <math.h>

// Amortized VI: per-row 3 MLPs (2->20->10->{4,4,6}), Cholesky reparam over
// P=8 samples, robot-arm FK likelihood, global mean.
//
// R5 insight: VGPR=44 proves the compiler sank the 16 float4 z-loads into
// the consuming loop -> serialized ~200-900cy load latency, 16 waves/CU
// can't hide it (VALU 26%, all pipes idle). Fix: explicit register prefetch
// of all z-data BEFORE the ~900-op MLP phase, pinned by sched_barrier(0);
// loads fly concurrently and MLP compute covers the latency.
//
// Constants folded: C_PRIOR + C_LIK + C_ENT = 12.838199208
#define C_ALL 12.838199208f

typedef float v2 __attribute__((ext_vector_type(2)));
static __device__ __forceinline__ v2 splat(float s) { return (v2){s, s}; }
#define FMA2 __builtin_elementwise_fma
#define MAX2 __builtin_elementwise_max

struct WPtrs { const float* p[18]; };

__device__ __forceinline__ float softplus_f(float x) {
    return fmaxf(x, 0.0f) + __logf(1.0f + __expf(-fabsf(x)));
}
__device__ __forceinline__ v2 sp2(v2 x) {
    v2 r; r.x = softplus_f(x.x); r.y = softplus_f(x.y); return r;
}

// Two-row packed MLP; weights wave-uniform (SGPR), broadcast into VOP3P.
template <int OD>
__device__ __forceinline__ void mlp2(const float* __restrict__ W1,
                                     const float* __restrict__ b1,
                                     const float* __restrict__ W2,
                                     const float* __restrict__ b2,
                                     const float* __restrict__ W3,
                                     const float* __restrict__ b3,
                                     v2 Y0, v2 Y1, v2* out) {
    v2 h2[10];
#pragma unroll
    for (int k = 0; k < 10; ++k) h2[k] = splat(b2[k]);
#pragma unroll
    for (int j = 0; j < 20; ++j) {
        const v2 h1 = MAX2(FMA2(Y0, splat(W1[j]), FMA2(Y1, splat(W1[20 + j]), splat(b1[j]))),
                           splat(0.0f));
#pragma unroll
        for (int k = 0; k < 10; ++k) h2[k] = FMA2(h1, splat(W2[j * 10 + k]), h2[k]);
    }
#pragma unroll
    for (int k = 0; k < 10; ++k) h2[k] = MAX2(h2[k], splat(0.0f));
#pragma unroll
    for (int d = 0; d < OD; ++d) out[d] = splat(b3[d]);
#pragma unroll
    for (int k = 0; k < 10; ++k) {
#pragma unroll
        for (int d = 0; d < OD; ++d) out[d] = FMA2(h2[k], splat(W3[k * OD + d]), out[d]);
    }
}

__global__ __launch_bounds__(256) void avi_kernel(
    const float* __restrict__ y, const float* __restrict__ zs, WPtrs wp,
    float* __restrict__ out, int N, float invN) {
    __shared__ float wsum[4];

    const int tid = threadIdx.x;
    const int na = blockIdx.x * 512 + tid;   // row A
    const int nb = na + 256;                 // row B (coalesced second slab)
    float rv = 0.0f;
    if (na < N) {
        const int mb = (nb < N) ? nb : na;   // tail: duplicate row A
        const float2 ya = *reinterpret_cast<const float2*>(y + 2 * (size_t)na);
        const float2 yb = *reinterpret_cast<const float2*>(y + 2 * (size_t)mb);

        // ---- prefetch: issue ALL z loads before any heavy compute ----
        const float4* zpa = reinterpret_cast<const float4*>(zs + (size_t)na * 32);
        const float4* zpb = reinterpret_cast<const float4*>(zs + (size_t)mb * 32);
        float4 za[8], zb[8];
#pragma unroll
        for (int p = 0; p < 8; ++p) za[p] = zpa[p];
#pragma unroll
        for (int p = 0; p < 8; ++p) zb[p] = zpb[p];
        __builtin_amdgcn_sched_barrier(0);   // don't sink the loads past here

        const v2 Y0 = {ya.x, yb.x};
        const v2 Y1 = {ya.y, yb.y};

        v2 mu[4], ld[4], lo[6];
        mlp2<4>(wp.p[0], wp.p[1], wp.p[2], wp.p[3], wp.p[4], wp.p[5], Y0, Y1, mu);
        mlp2<4>(wp.p[6], wp.p[7], wp.p[8], wp.p[9], wp.p[10], wp.p[11], Y0, Y1, ld);
        mlp2<6>(wp.p[12], wp.p[13], wp.p[14], wp.p[15], wp.p[16], wp.p[17], Y0, Y1, lo);

        const v2 d0 = sp2(ld[0]), d1 = sp2(ld[1]), d2 = sp2(ld[2]), d3 = sp2(ld[3]);
        const v2 prod = d0 * d1 * d2 * d3;
        const v2 L10 = lo[0], L20 = lo[1], L21 = lo[2];
        const v2 L30 = lo[3], L31 = lo[4], L32 = lo[5];

        v2 acc = splat(0.0f);
#pragma unroll
        for (int p = 0; p < 8; ++p) {
            const v2 zx = {za[p].x, zb[p].x}, zy = {za[p].y, zb[p].y};
            const v2 zz = {za[p].z, zb[p].z}, zw = {za[p].w, zb[p].w};

            const v2 xi0 = FMA2(d0, zx, mu[0]);
            const v2 xi1 = FMA2(d1, zy, FMA2(L10, zx, mu[1]));
            const v2 xi2 = FMA2(d2, zz, FMA2(L21, zy, FMA2(L20, zx, mu[2])));
            const v2 xi3 = FMA2(d3, zw, FMA2(L32, zz, FMA2(L31, zy, FMA2(L30, zx, mu[3]))));

            const v2 a1 = xi1, a2 = xi1 + xi2, a3 = a2 + xi3;
            float s1x, c1x, s1y, c1y, s2x, c2x, s2y, c2y, s3x, c3x, s3y, c3y;
            __sincosf(a1.x, &s1x, &c1x);
            __sincosf(a1.y, &s1y, &c1y);
            __sincosf(a2.x, &s2x, &c2x);
            __sincosf(a2.y, &s2y, &c2y);
            __sincosf(a3.x, &s3x, &c3x);
            __sincosf(a3.y, &s3y, &c3y);
            const v2 s1 = {s1x, s1y}, c1 = {c1x, c1y};
            const v2 s2 = {s2x, s2y}, c2 = {c2x, c2y};
            const v2 s3 = {s3x, s3y}, c3 = {c3x, c3y};

            const v2 half = splat(0.5f);
            const v2 px = FMA2(half, c1, FMA2(half, c2, c3));
            const v2 py = xi0 + FMA2(half, s1, FMA2(half, s2, s3));

            const v2 q0 = xi0 * splat(4.0f), q1 = xi1 * splat(2.0f);
            const v2 q2 = xi2 * splat(2.0f), q3 = xi3 * splat(2.0f);
            const v2 pq = FMA2(q0, q0, FMA2(q1, q1, FMA2(q2, q2, q3 * q3)));
            const v2 r0 = (Y0 - px) * splat(100.0f);
            const v2 r1 = (Y1 - py) * splat(100.0f);
            acc = FMA2(splat(-0.5f), pq + FMA2(r0, r0, r1 * r1), acc);
        }
        if (nb < N) {
            rv = fmaf(0.125f, acc.x, C_ALL + __logf(prod.x))
               + fmaf(0.125f, acc.y, C_ALL + __logf(prod.y));
        } else {
            rv = fmaf(0.125f, acc.x, C_ALL + __logf(prod.x));
        }
    }

    // wave (64) shuffle reduce, then cross-wave via LDS
#pragma unroll
    for (int d = 32; d > 0; d >>= 1) rv += __shfl_down(rv, d);
    if ((tid & 63) == 0) wsum[tid >> 6] = rv;
    __syncthreads();
    if (tid == 0) {
        const float s = wsum[0] + wsum[1] + wsum[2] + wsum[3];
        atomicAdd(out, s * invN);
    }
}

extern "C" void kernel_launch(void* const* d_in, const int* in_sizes, int n_in,
                              void* d_out, int out_size, void* d_ws, size_t ws_size,
                              hipStream_t stream) {
    const float* y = (const float*)d_in[0];
    const float* zs = (const float*)d_in[1];
    WPtrs wp;
    for (int i = 0; i < 18; ++i) wp.p[i] = (const float*)d_in[2 + i];
    float* out = (float*)d_out;
    const int N = in_sizes[0] / 2;

    hipMemsetAsync(out, 0, sizeof(float), stream);
    const int blocks = (N + 511) / 512;
    avi_kernel<<<blocks, 256, 0, stream>>>(y, zs, wp, out, N, 1.0f / (float)N);
}